// Round 5
// baseline (1187.030 us; speedup 1.0000x reference)
//
#include <hip/hip_runtime.h>
#include <cstddef>
#include <cstdint>
#include <math.h>

#define BB   4
#define TT   2048
#define CCH  1024
#define HH   16
#define DD   64
#define CSZ  16
#define NTC  128
#define EPSF 1e-5f

typedef __attribute__((ext_vector_type(8))) short bf16x8;
typedef __attribute__((ext_vector_type(4))) float f32x4;

// ---------- split-float helpers: f32 ≈ hi(bf16) + lo(bf16), packed (hi | lo<<16) ----------
__device__ __forceinline__ uint32_t pack_split(float f) {
  uint32_t b = __float_as_uint(f);
  uint32_t uh = (b + 0x7fffu + ((b >> 16) & 1u)) >> 16;   // RNE bf16 of f
  float fh = __uint_as_float(uh << 16);
  float r = f - fh;
  return uh | (__float_as_uint(r) & 0xffff0000u);          // lo = trunc bf16 of residual
}
__device__ __forceinline__ float unpack_f(uint32_t u) {
  return __uint_as_float(u << 16) + __uint_as_float(u & 0xffff0000u);
}

// Wave64 sum via DPP (VALU pipe, not LDS pipe).
__device__ __forceinline__ float wave_sum(float x) {
  float v = x;
  v += __int_as_float(__builtin_amdgcn_update_dpp(0, __float_as_int(v), 0x111, 0xf, 0xf, true));
  v += __int_as_float(__builtin_amdgcn_update_dpp(0, __float_as_int(v), 0x112, 0xf, 0xf, true));
  v += __int_as_float(__builtin_amdgcn_update_dpp(0, __float_as_int(v), 0x114, 0xf, 0xf, true));
  v += __int_as_float(__builtin_amdgcn_update_dpp(0, __float_as_int(v), 0x118, 0xf, 0xf, true));
  v += __int_as_float(__builtin_amdgcn_update_dpp(0, __float_as_int(v), 0x142, 0xa, 0xf, true));
  v += __int_as_float(__builtin_amdgcn_update_dpp(0, __float_as_int(v), 0x143, 0xc, 0xf, true));
  return __int_as_float(__builtin_amdgcn_readlane(__float_as_int(v), 63));
}

__device__ __forceinline__ float sigmoidf_(float x) {
  return 1.f / (1.f + expf(-x));
}

// ---------- transpose + split: W (KxN f32) -> Wt (NxK packed u32) ----------
__global__ __launch_bounds__(256) void split_transpose(
    const float* __restrict__ W, uint32_t* __restrict__ Wt, int K, int N) {
  __shared__ float t[32][33];
  const int n0 = blockIdx.x * 32, k0 = blockIdx.y * 32;
  const int tx = threadIdx.x & 31, ty = threadIdx.x >> 5;  // ty 0..7
#pragma unroll
  for (int i = 0; i < 4; i++)
    t[ty + i * 8][tx] = W[(size_t)(k0 + ty + i * 8) * N + n0 + tx];
  __syncthreads();
#pragma unroll
  for (int i = 0; i < 4; i++)
    Wt[(size_t)(n0 + ty + i * 8) * K + k0 + tx] = pack_split(t[tx][ty + i * 8]);
}

// ---------- split-bf16 MFMA GEMM: C = A @ Bt^T + bias ----------
template<bool A_PACKED, bool C_PACKED>
__global__ __launch_bounds__(256) void gemm_split(
    const void* __restrict__ Av, int lda,
    const uint32_t* __restrict__ Bt,
    const float* __restrict__ bias,
    void* __restrict__ Cv, int M, int N, int K) {
  __shared__ unsigned short Ahi[128][40];
  __shared__ unsigned short Alo[128][40];
  __shared__ unsigned short Bhi[128][40];
  __shared__ unsigned short Blo[128][40];

  const int tid = threadIdx.x;
  const int row0 = blockIdx.y * 128;
  const int col0 = blockIdx.x * 128;
  const int wv = tid >> 6;
  const int l  = tid & 63;
  const int wr = wv >> 1, wc = wv & 1;
  const int lrow = l & 15;
  const int kgrp = (l >> 4) * 8;

  const int sr = tid >> 1;
  const int sk = (tid & 1) * 16;

  f32x4 acc[4][4];
#pragma unroll
  for (int i = 0; i < 4; i++)
#pragma unroll
    for (int j = 0; j < 4; j++) acc[i][j] = (f32x4){0.f, 0.f, 0.f, 0.f};

  for (int k0 = 0; k0 < K; k0 += 32) {
    {
      uint32_t hp[8], lp[8];
      if (A_PACKED) {
        const uint32_t* Ap = (const uint32_t*)Av + (size_t)(row0 + sr) * lda + k0 + sk;
        uint32_t u[16];
#pragma unroll
        for (int i = 0; i < 4; i++) *(uint4*)&u[i * 4] = *(const uint4*)(Ap + i * 4);
#pragma unroll
        for (int j = 0; j < 8; j++) {
          hp[j] = (u[2 * j] & 0xffffu) | (u[2 * j + 1] << 16);
          lp[j] = (u[2 * j] >> 16) | (u[2 * j + 1] & 0xffff0000u);
        }
      } else {
        const float* Ap = (const float*)Av + (size_t)(row0 + sr) * lda + k0 + sk;
        float f[16];
#pragma unroll
        for (int i = 0; i < 4; i++) *(float4*)&f[i * 4] = *(const float4*)(Ap + i * 4);
        uint32_t uh[16], ulr[16];
#pragma unroll
        for (int j = 0; j < 16; j++) {
          uint32_t b = __float_as_uint(f[j]);
          uint32_t h = (b + 0x7fffu + ((b >> 16) & 1u)) >> 16;
          uh[j] = h;
          ulr[j] = __float_as_uint(f[j] - __uint_as_float(h << 16));
        }
#pragma unroll
        for (int j = 0; j < 8; j++) {
          hp[j] = uh[2 * j] | (uh[2 * j + 1] << 16);
          lp[j] = (ulr[2 * j] >> 16) | (ulr[2 * j + 1] & 0xffff0000u);
        }
      }
      *(uint4*)&Ahi[sr][sk]     = *(uint4*)&hp[0];
      *(uint4*)&Ahi[sr][sk + 8] = *(uint4*)&hp[4];
      *(uint4*)&Alo[sr][sk]     = *(uint4*)&lp[0];
      *(uint4*)&Alo[sr][sk + 8] = *(uint4*)&lp[4];
    }
    {
      const uint32_t* Bp = Bt + (size_t)(col0 + sr) * K + k0 + sk;
      uint32_t u[16], hp[8], lp[8];
#pragma unroll
      for (int i = 0; i < 4; i++) *(uint4*)&u[i * 4] = *(const uint4*)(Bp + i * 4);
#pragma unroll
      for (int j = 0; j < 8; j++) {
        hp[j] = (u[2 * j] & 0xffffu) | (u[2 * j + 1] << 16);
        lp[j] = (u[2 * j] >> 16) | (u[2 * j + 1] & 0xffff0000u);
      }
      *(uint4*)&Bhi[sr][sk]     = *(uint4*)&hp[0];
      *(uint4*)&Bhi[sr][sk + 8] = *(uint4*)&hp[4];
      *(uint4*)&Blo[sr][sk]     = *(uint4*)&lp[0];
      *(uint4*)&Blo[sr][sk + 8] = *(uint4*)&lp[4];
    }
    __syncthreads();

    bf16x8 bh[4], bl[4];
#pragma unroll
    for (int j = 0; j < 4; j++) {
      bh[j] = *(const bf16x8*)&Bhi[wc * 64 + j * 16 + lrow][kgrp];
      bl[j] = *(const bf16x8*)&Blo[wc * 64 + j * 16 + lrow][kgrp];
    }
#pragma unroll
    for (int i = 0; i < 4; i++) {
      bf16x8 ah = *(const bf16x8*)&Ahi[wr * 64 + i * 16 + lrow][kgrp];
      bf16x8 al = *(const bf16x8*)&Alo[wr * 64 + i * 16 + lrow][kgrp];
#pragma unroll
      for (int j = 0; j < 4; j++) {
        acc[i][j] = __builtin_amdgcn_mfma_f32_16x16x32_bf16(ah, bh[j], acc[i][j], 0, 0, 0);
        acc[i][j] = __builtin_amdgcn_mfma_f32_16x16x32_bf16(ah, bl[j], acc[i][j], 0, 0, 0);
        acc[i][j] = __builtin_amdgcn_mfma_f32_16x16x32_bf16(al, bh[j], acc[i][j], 0, 0, 0);
      }
    }
    __syncthreads();
  }

  const int crow4 = (l >> 4) * 4;
#pragma unroll
  for (int i = 0; i < 4; i++) {
#pragma unroll
    for (int j = 0; j < 4; j++) {
      const int col = col0 + wc * 64 + j * 16 + lrow;
      const float bv = bias[col];
      const int rowb = row0 + wr * 64 + i * 16 + crow4;
#pragma unroll
      for (int r = 0; r < 4; r++) {
        float v = acc[i][j][r] + bv;
        size_t off = (size_t)(rowb + r) * N + col;
        if (C_PACKED) ((uint32_t*)Cv)[off] = pack_split(v);
        else          ((float*)Cv)[off] = v;
      }
    }
  }
}

// ---------- fp32 VALU GEMM (tiny N=48 param GEMM) ----------
__global__ __launch_bounds__(256) void gemm_f32(
    const float* __restrict__ A, int lda,
    const float* __restrict__ W,
    const float* __restrict__ bias,
    float* __restrict__ C, int M, int N, int K) {
  __shared__ float As[16][132];
  __shared__ float Bs[16][128];
  const int tid  = threadIdx.x;
  const int row0 = blockIdx.y * 128;
  const int col0 = blockIdx.x * 128;
  const int ty = tid >> 4;
  const int tx = tid & 15;
  const int a_r = tid >> 2;
  const int a_k = (tid & 3) << 2;
  const int b_r = tid >> 5;
  const int b_c = (tid & 31) << 2;

  float acc[8][8];
#pragma unroll
  for (int i = 0; i < 8; i++)
#pragma unroll
    for (int j = 0; j < 8; j++) acc[i][j] = 0.f;

  float4 areg[2], breg[2];
  const int gc = col0 + b_c;
#pragma unroll
  for (int i = 0; i < 2; i++)
    areg[i] = *(const float4*)(A + (size_t)(row0 + a_r + i * 64) * lda + a_k);
#pragma unroll
  for (int i = 0; i < 2; i++) {
    breg[i] = make_float4(0.f, 0.f, 0.f, 0.f);
    if (gc < N) breg[i] = *(const float4*)(W + (size_t)(b_r + i * 8) * N + gc);
  }

  for (int k0 = 0; k0 < K; k0 += 16) {
#pragma unroll
    for (int i = 0; i < 2; i++) {
      int r = a_r + i * 64;
      As[a_k + 0][r] = areg[i].x;
      As[a_k + 1][r] = areg[i].y;
      As[a_k + 2][r] = areg[i].z;
      As[a_k + 3][r] = areg[i].w;
    }
#pragma unroll
    for (int i = 0; i < 2; i++) *(float4*)(&Bs[b_r + i * 8][b_c]) = breg[i];
    __syncthreads();

    if (k0 + 16 < K) {
#pragma unroll
      for (int i = 0; i < 2; i++)
        areg[i] = *(const float4*)(A + (size_t)(row0 + a_r + i * 64) * lda + (k0 + 16 + a_k));
#pragma unroll
      for (int i = 0; i < 2; i++) {
        breg[i] = make_float4(0.f, 0.f, 0.f, 0.f);
        if (gc < N) breg[i] = *(const float4*)(W + (size_t)(k0 + 16 + b_r + i * 8) * N + gc);
      }
    }

#pragma unroll
    for (int kk = 0; kk < 16; kk++) {
      float af[8], bf[8];
      *(float4*)&af[0] = *(const float4*)&As[kk][ty * 8];
      *(float4*)&af[4] = *(const float4*)&As[kk][ty * 8 + 4];
      *(float4*)&bf[0] = *(const float4*)&Bs[kk][tx * 8];
      *(float4*)&bf[4] = *(const float4*)&Bs[kk][tx * 8 + 4];
#pragma unroll
      for (int i = 0; i < 8; i++)
#pragma unroll
        for (int j = 0; j < 8; j++) acc[i][j] += af[i] * bf[j];
    }
    __syncthreads();
  }
#pragma unroll
  for (int i = 0; i < 8; i++) {
    int r = row0 + ty * 8 + i;
#pragma unroll
    for (int j0 = 0; j0 < 8; j0 += 4) {
      int cc = col0 + tx * 8 + j0;
      if (cc < N) {
        float4 ov;
        ov.x = acc[i][j0 + 0] + bias[cc + 0];
        ov.y = acc[i][j0 + 1] + bias[cc + 1];
        ov.z = acc[i][j0 + 2] + bias[cc + 2];
        ov.w = acc[i][j0 + 3] + bias[cc + 3];
        *(float4*)(C + (size_t)r * N + cc) = ov;
      }
    }
  }
}

// L2-normalize packed q/k rows (length 64) in-place. One wave per row.
__global__ __launch_bounds__(256) void normalize_qk(uint32_t* __restrict__ qkv) {
  const int idx = blockIdx.x * 4 + (threadIdx.x >> 6);
  const int l = threadIdx.x & 63;
  const int rowBT = idx >> 5;
  const int rem = idx & 31;
  const int which = rem >> 4;
  const int h = rem & 15;
  const size_t addr = (size_t)rowBT * 3072 + (size_t)which * 1024 + h * 64 + l;
  float v = unpack_f(qkv[addr]);
  float ss = wave_sum(v * v);
  float sc = 1.f / fmaxf(sqrtf(ss), 1e-12f);
  qkv[addr] = pack_split(v * sc);
}

// ===================== Titans recurrence — closed-form chunk (MFMA) =====================
// One block per (b,h), 512 threads = 8 waves. State S,M (64x64, f32) lives in REGISTERS:
// thread (wv,l) owns rows d = wv*8+r (r<8), column e = l — exact f32 recurrence, no
// bf16 error accumulation. Per chunk (S0 = chunk-start state, used by ALL tokens):
//   KH   = K @ S0                          (MFMA, split-bf16)
//   DKH  = LN_bwd(LN(KH), v)               (VALU + DPP reductions)
//   G    = Q @ K^T ; W = C ∘ G (causal)    (MFMA; C from scalar recurrences)
//   O    = diag(P)·QS0 + diag(B)·QM0 − W @ DKH   (MFMA)
//   S_new = P15·S0 + B15·M0 − Σ_t c_t k_t⊗dkh_t  (rank-16, VALU, f32)
//   M_new = E15·M0 − Σ_t r_t k_t⊗dkh_t
// Coefficients: E_t=∏η, P_t=∏β (β=1−α), B_t = β_t·B_{t−1}+E_t,
// C[t][l] = θ_l·D with D = β_t·D+R, R = η_t·R (R=D=1 at t=l); c_l = C[15][l], r_l = θ_l·R(15,l).
__global__ __launch_bounds__(512) void titans_rec(
    uint32_t* __restrict__ qkv, const float* __restrict__ p,
    const float* __restrict__ w, const float* __restrict__ bparm) {
  const int bh = blockIdx.x;
  const int b = bh >> 4;
  const int h = bh & 15;
  const int tid = threadIdx.x;
  const int wv = tid >> 6;   // 0..7
  const int l = tid & 63;
  const int lr = l & 15;
  const int kg = (l >> 4) * 8;

  // split planes ([x][k] layout serves both MFMA A- and B-fragments)
  __shared__ unsigned short Sthi[64][72], Stlo[64][72];   // S^T[e][d]
  __shared__ unsigned short Mthi[64][72], Mtlo[64][72];   // M^T[e][d]
  __shared__ unsigned short Khi[16][72], Klo[16][72];     // K[t][d]
  __shared__ unsigned short Qhi[16][72], Qlo[16][72];     // Q[t][d]
  __shared__ unsigned short DThi[64][32], DTlo[64][32];   // dkh^T[e][t] (t 16..31 zero)
  __shared__ unsigned short Whi[16][32], Wlo[16][32];     // W[t][l]    (l 16..31 zero)
  __shared__ float k_s[CSZ][DD], v_s[CSZ][DD];            // f32 copies
  __shared__ float kh_s[CSZ][66], o_s[CSZ][66];
  __shared__ float dkh_s[CSZ][DD];
  __shared__ float g_s[CSZ][CSZ];
  __shared__ float c_s[CSZ][CSZ];                         // C[t][l]
  __shared__ float a_s[CSZ], b_s[CSZ], rvec_s[CSZ];
  __shared__ float sc_s[4];                               // P15, B15, E15
  __shared__ float4 prm_s[CSZ];                           // th, al, et

  float S[8], M[8];
#pragma unroll
  for (int r = 0; r < 8; r++) { S[r] = 0.f; M[r] = 0.f; }

  const float w_l = w[h * DD + l];
  const float b_l = bparm[h * DD + l];

  uint32_t* qbase = qkv + (size_t)(b * TT) * 3072 + h * DD;
  const float* pbase = p + (size_t)(b * TT) * 48 + h * 3;

  // ---- prologue: zero planes, load+commit chunk 0 ----
  for (int i = tid; i < 2304; i += 512) {
    ((uint32_t*)Sthi)[i] = 0; ((uint32_t*)Stlo)[i] = 0;
    ((uint32_t*)Mthi)[i] = 0; ((uint32_t*)Mtlo)[i] = 0;
  }
  for (int i = tid; i < 1024; i += 512) { ((uint32_t*)DThi)[i] = 0; ((uint32_t*)DTlo)[i] = 0; }
  if (tid < 256) { ((uint32_t*)Whi)[tid] = 0; ((uint32_t*)Wlo)[tid] = 0; }
  {
#pragma unroll
    for (int i = 0; i < 2; i++) {
      const int row = wv + i * 8;
      size_t roff = (size_t)row * 3072 + l;
      uint32_t uq = qbase[roff], uk = qbase[roff + 1024], uv = qbase[roff + 2048];
      k_s[row][l] = unpack_f(uk);
      v_s[row][l] = unpack_f(uv);
      Khi[row][l] = (unsigned short)(uk & 0xffffu); Klo[row][l] = (unsigned short)(uk >> 16);
      Qhi[row][l] = (unsigned short)(uq & 0xffffu); Qlo[row][l] = (unsigned short)(uq >> 16);
    }
    if (tid < CSZ) {
      const float* pp = pbase + (size_t)tid * 48;
      prm_s[tid] = make_float4(sigmoidf_(pp[0]), sigmoidf_(pp[1]), sigmoidf_(pp[2]), 0.f);
    }
  }
  __syncthreads();

  uint32_t rq[2], rk[2], rv[2];
  float rp0 = 0.f, rp1 = 0.f, rp2 = 0.f;

  for (int nt = 0; nt < NTC; nt++) {
    f32x4 accS = (f32x4){0.f, 0.f, 0.f, 0.f};
    f32x4 accM = (f32x4){0.f, 0.f, 0.f, 0.f};

    // ---- P1: prefetch issue; MFMA KH / G / QS0 / QM0; coefficient recurrences ----
    if (nt + 1 < NTC) {
#pragma unroll
      for (int i = 0; i < 2; i++) {
        size_t roff = (size_t)((nt + 1) * CSZ + wv + i * 8) * 3072 + l;
        rq[i] = qbase[roff]; rk[i] = qbase[roff + 1024]; rv[i] = qbase[roff + 2048];
      }
      if (tid < CSZ) {
        const float* pp = pbase + (size_t)((nt + 1) * CSZ + tid) * 48;
        rp0 = pp[0]; rp1 = pp[1]; rp2 = pp[2];
      }
    }
    if (wv < 4) {
      // KH e-tile wv: A = K, B = S^T planes
      f32x4 acc = (f32x4){0.f, 0.f, 0.f, 0.f};
#pragma unroll
      for (int ks = 0; ks < 2; ks++) {
        const int ko = kg + ks * 32;
        bf16x8 ah = *(const bf16x8*)&Khi[lr][ko];
        bf16x8 aL = *(const bf16x8*)&Klo[lr][ko];
        bf16x8 bh = *(const bf16x8*)&Sthi[wv * 16 + lr][ko];
        bf16x8 bL = *(const bf16x8*)&Stlo[wv * 16 + lr][ko];
        acc = __builtin_amdgcn_mfma_f32_16x16x32_bf16(ah, bh, acc, 0, 0, 0);
        acc = __builtin_amdgcn_mfma_f32_16x16x32_bf16(ah, bL, acc, 0, 0, 0);
        acc = __builtin_amdgcn_mfma_f32_16x16x32_bf16(aL, bh, acc, 0, 0, 0);
      }
#pragma unroll
      for (int r = 0; r < 4; r++) kh_s[(l >> 4) * 4 + r][wv * 16 + lr] = acc[r];
    } else {
      const int et = (wv - 4) * 16 + lr;
      f32x4 accG = (f32x4){0.f, 0.f, 0.f, 0.f};
#pragma unroll
      for (int ks = 0; ks < 2; ks++) {
        const int ko = kg + ks * 32;
        bf16x8 ah = *(const bf16x8*)&Qhi[lr][ko];
        bf16x8 aL = *(const bf16x8*)&Qlo[lr][ko];
        bf16x8 bh = *(const bf16x8*)&Sthi[et][ko];
        bf16x8 bL = *(const bf16x8*)&Stlo[et][ko];
        accS = __builtin_amdgcn_mfma_f32_16x16x32_bf16(ah, bh, accS, 0, 0, 0);
        accS = __builtin_amdgcn_mfma_f32_16x16x32_bf16(ah, bL, accS, 0, 0, 0);
        accS = __builtin_amdgcn_mfma_f32_16x16x32_bf16(aL, bh, accS, 0, 0, 0);
        bh = *(const bf16x8*)&Mthi[et][ko];
        bL = *(const bf16x8*)&Mtlo[et][ko];
        accM = __builtin_amdgcn_mfma_f32_16x16x32_bf16(ah, bh, accM, 0, 0, 0);
        accM = __builtin_amdgcn_mfma_f32_16x16x32_bf16(ah, bL, accM, 0, 0, 0);
        accM = __builtin_amdgcn_mfma_f32_16x16x32_bf16(aL, bh, accM, 0, 0, 0);
        if (wv == 4) {
          bf16x8 gh = *(const bf16x8*)&Khi[lr][ko];
          bf16x8 gL = *(const bf16x8*)&Klo[lr][ko];
          accG = __builtin_amdgcn_mfma_f32_16x16x32_bf16(ah, gh, accG, 0, 0, 0);
          accG = __builtin_amdgcn_mfma_f32_16x16x32_bf16(ah, gL, accG, 0, 0, 0);
          accG = __builtin_amdgcn_mfma_f32_16x16x32_bf16(aL, gh, accG, 0, 0, 0);
        }
      }
      if (wv == 4) {
#pragma unroll
        for (int r = 0; r < 4; r++) g_s[(l >> 4) * 4 + r][lr] = accG[r];
      }
    }
    if (wv == 5 && l < 16) {
      float A = 1.f, Bc = 0.f, E = 1.f;
      for (int i = 0; i <= l; i++) {
        float4 pr = prm_s[i];
        float bet = 1.f - pr.y;
        E *= pr.z;
        A *= bet;
        Bc = bet * Bc + E;
      }
      a_s[l] = A; b_s[l] = Bc;
      if (l == 15) { sc_s[0] = A; sc_s[1] = Bc; sc_s[2] = E; }
      float th_l = prm_s[l].x;
      float R = 1.f, D = 1.f;
      c_s[l][l] = th_l;
      for (int t = l + 1; t < 16; t++) {
        float4 pr = prm_s[t];
        R *= pr.z;
        D = (1.f - pr.y) * D + R;
        c_s[t][l] = th_l * D;
      }
      rvec_s[l] = th_l * R;
    }
    __syncthreads();

    // ---- P2: LN fwd+bwd (2 rows/wave); W = C∘G build ----
#pragma unroll
    for (int i = 0; i < 2; i++) {
      const int c = wv + i * 8;
      float kh = kh_s[c][l];
      float mu = wave_sum(kh) * (1.f / 64.f);
      float xc = kh - mu;
      float var = wave_sum(xc * xc) * (1.f / 64.f);
      float rstd = rsqrtf(var + EPSF);
      float xhat = xc * rstd;
      float y = xhat * w_l + b_l;
      float dy = 2.f * (y - v_s[c][l]);
      float wdy = dy * w_l;
      float c1 = wave_sum(xhat * wdy) * (1.f / 64.f);
      float c2 = wave_sum(wdy) * (1.f / 64.f);
      dkh_s[c][l] = (wdy - xhat * c1 - c2) * rstd;
    }
    if (tid < 256) {
      const int t = tid >> 4, lc = tid & 15;
      float wval = (lc <= t) ? c_s[t][lc] * g_s[t][lc] : 0.f;
      uint32_t ps = pack_split(wval);
      Whi[t][lc] = (unsigned short)(ps & 0xffffu);
      Wlo[t][lc] = (unsigned short)(ps >> 16);
    }
    __syncthreads();

    // ---- P3: dkh^T planes ----
    {
      const int idx = tid * 2;
      const int e = idx >> 4, t = idx & 15;
      uint32_t p0 = pack_split(dkh_s[t][e]);
      uint32_t p1 = pack_split(dkh_s[t + 1][e]);
      *(uint32_t*)&DThi[e][t] = (p0 & 0xffffu) | ((p1 & 0xffffu) << 16);
      *(uint32_t*)&DTlo[e][t] = (p0 >> 16) | (p1 & 0xffff0000u);
    }
    __syncthreads();

    // ---- P4: scan-term MFMA + O combine (w4-7); rank-16 state update (all, f32) ----
    if (wv >= 4) {
      const int et = (wv - 4) * 16 + lr;
      f32x4 accO = (f32x4){0.f, 0.f, 0.f, 0.f};
      bf16x8 ah = *(const bf16x8*)&Whi[lr][kg];
      bf16x8 aL = *(const bf16x8*)&Wlo[lr][kg];
      bf16x8 bh = *(const bf16x8*)&DThi[et][kg];
      bf16x8 bL = *(const bf16x8*)&DTlo[et][kg];
      accO = __builtin_amdgcn_mfma_f32_16x16x32_bf16(ah, bh, accO, 0, 0, 0);
      accO = __builtin_amdgcn_mfma_f32_16x16x32_bf16(ah, bL, accO, 0, 0, 0);
      accO = __builtin_amdgcn_mfma_f32_16x16x32_bf16(aL, bh, accO, 0, 0, 0);
#pragma unroll
      for (int r = 0; r < 4; r++) {
        const int t = (l >> 4) * 4 + r;
        o_s[t][et] = a_s[t] * accS[r] + b_s[t] * accM[r] - accO[r];
      }
    }
    {
      const float a15 = sc_s[0], b15 = sc_s[1], e15 = sc_s[2];
      float sS[8], sM[8];
#pragma unroll
      for (int r = 0; r < 8; r++) { sS[r] = 0.f; sM[r] = 0.f; }
#pragma unroll 4
      for (int t = 0; t < 16; t++) {
        float dt = dkh_s[t][l];
        float cd = c_s[15][t] * dt;
        float rd = rvec_s[t] * dt;
        const float* kp = &k_s[t][wv * 8];
        float4 ka = *(const float4*)kp;
        float4 kb = *(const float4*)(kp + 4);
        sS[0] += cd * ka.x; sM[0] += rd * ka.x;
        sS[1] += cd * ka.y; sM[1] += rd * ka.y;
        sS[2] += cd * ka.z; sM[2] += rd * ka.z;
        sS[3] += cd * ka.w; sM[3] += rd * ka.w;
        sS[4] += cd * kb.x; sM[4] += rd * kb.x;
        sS[5] += cd * kb.y; sM[5] += rd * kb.y;
        sS[6] += cd * kb.z; sM[6] += rd * kb.z;
        sS[7] += cd * kb.w; sM[7] += rd * kb.w;
      }
#pragma unroll
      for (int r = 0; r < 8; r++) {
        float So = S[r];
        S[r] = a15 * So + b15 * M[r] - sS[r];
        M[r] = e15 * M[r] - sM[r];
      }
    }
    __syncthreads();

    // ---- P5+P6: pack state planes; commit next-chunk tiles; LN(o) + store ----
    {
      uint32_t ps[8], pm[8];
#pragma unroll
      for (int r = 0; r < 8; r++) { ps[r] = pack_split(S[r]); pm[r] = pack_split(M[r]); }
      uint4 sh, sl, mh, ml;
      sh.x = (ps[0] & 0xffffu) | (ps[1] << 16);  sl.x = (ps[0] >> 16) | (ps[1] & 0xffff0000u);
      sh.y = (ps[2] & 0xffffu) | (ps[3] << 16);  sl.y = (ps[2] >> 16) | (ps[3] & 0xffff0000u);
      sh.z = (ps[4] & 0xffffu) | (ps[5] << 16);  sl.z = (ps[4] >> 16) | (ps[5] & 0xffff0000u);
      sh.w = (ps[6] & 0xffffu) | (ps[7] << 16);  sl.w = (ps[6] >> 16) | (ps[7] & 0xffff0000u);
      mh.x = (pm[0] & 0xffffu) | (pm[1] << 16);  ml.x = (pm[0] >> 16) | (pm[1] & 0xffff0000u);
      mh.y = (pm[2] & 0xffffu) | (pm[3] << 16);  ml.y = (pm[2] >> 16) | (pm[3] & 0xffff0000u);
      mh.z = (pm[4] & 0xffffu) | (pm[5] << 16);  ml.z = (pm[4] >> 16) | (pm[5] & 0xffff0000u);
      mh.w = (pm[6] & 0xffffu) | (pm[7] << 16);  ml.w = (pm[6] >> 16) | (pm[7] & 0xffff0000u);
      *(uint4*)&Sthi[l][wv * 8] = sh;  *(uint4*)&Stlo[l][wv * 8] = sl;
      *(uint4*)&Mthi[l][wv * 8] = mh;  *(uint4*)&Mtlo[l][wv * 8] = ml;
    }
    if (nt + 1 < NTC) {
#pragma unroll
      for (int i = 0; i < 2; i++) {
        const int row = wv + i * 8;
        k_s[row][l] = unpack_f(rk[i]);
        v_s[row][l] = unpack_f(rv[i]);
        Khi[row][l] = (unsigned short)(rk[i] & 0xffffu); Klo[row][l] = (unsigned short)(rk[i] >> 16);
        Qhi[row][l] = (unsigned short)(rq[i] & 0xffffu); Qlo[row][l] = (unsigned short)(rq[i] >> 16);
      }
      if (tid < CSZ)
        prm_s[tid] = make_float4(sigmoidf_(rp0), sigmoidf_(rp1), sigmoidf_(rp2), 0.f);
    }
#pragma unroll
    for (int i = 0; i < 2; i++) {
      const int t = wv + i * 8;
      float o = o_s[t][l];
      float mu = wave_sum(o) * (1.f / 64.f);
      float xc = o - mu;
      float var = wave_sum(xc * xc) * (1.f / 64.f);
      float rstd = rsqrtf(var + EPSF);
      float y = xc * rstd * w_l + b_l;
      qbase[(size_t)(nt * CSZ + t) * 3072 + 2048 + l] = pack_split(y);
    }
    __syncthreads();
  }
}

extern "C" void kernel_launch(void* const* d_in, const int* in_sizes, int n_in,
                              void* d_out, int out_size, void* d_ws, size_t ws_size,
                              hipStream_t stream) {
  const float* x      = (const float*)d_in[0];
  const float* W_attn = (const float*)d_in[1];
  const float* b_attn = (const float*)d_in[2];
  const float* W_parm = (const float*)d_in[3];
  const float* b_parm = (const float*)d_in[4];
  const float* W_proj = (const float*)d_in[5];
  const float* b_proj = (const float*)d_in[6];
  const float* w      = (const float*)d_in[7];
  const float* bb     = (const float*)d_in[8];
  float* out = (float*)d_out;

  const int M = BB * TT;        // 8192
  float* qkv = (float*)d_ws;                               // M x 3072 (packed u32)
  float* pbf = qkv + (size_t)M * 3072;                     // M x 48 f32
  uint32_t* wattn_t = (uint32_t*)(pbf + (size_t)M * 48);   // 3072 x 1024 packed
  uint32_t* wproj_t = wattn_t + (size_t)3072 * 1024;       // 1024 x 1024 packed

  split_transpose<<<dim3(3072 / 32, 1024 / 32), 256, 0, stream>>>(W_attn, wattn_t, 1024, 3072);
  split_transpose<<<dim3(1024 / 32, 1024 / 32), 256, 0, stream>>>(W_proj, wproj_t, 1024, 1024);

  gemm_split<false, true><<<dim3(3072 / 128, M / 128), 256, 0, stream>>>(
      x, CCH, wattn_t, b_attn, qkv, M, 3072, CCH);
  gemm_f32<<<dim3(1, M / 128), 256, 0, stream>>>(x, CCH, W_parm, b_parm, pbf, M, 48, CCH);
  normalize_qk<<<(M * 2 * HH) / 4, 256, 0, stream>>>((uint32_t*)qkv);
  titans_rec<<<BB * HH, 512, 0, stream>>>((uint32_t*)qkv, pbf, w, bb);
  gemm_split<true, false><<<dim3(CCH / 128, M / 128), 256, 0, stream>>>(
      (uint32_t*)qkv + 2048, 3072, wproj_t, b_proj, out, M, CCH, CCH);
}